// Round 3
// baseline (1166.082 us; speedup 1.0000x reference)
//
#include <hip/hip_runtime.h>
#include <math.h>

#define Bsz 512
#define Tt  2048
#define Hd  128
#define Ed  256
#define Vv  34

// d_out flat layout (floats)
#define OUT_OUT 0
#define OUT_C   17408
#define OUT_SH0 82944
#define OUT_SH1 148480
#define OUT_SC0 214016
#define OUT_SC1 279552
#define OUT_ATT 345088

__device__ __forceinline__ float sigm(float x) { return 1.0f / (1.0f + expf(-x)); }

// ---------------------------------------------------------------------------
// Fused: LSTM0 -> LSTM1 -> attention(scores/softmax/context) -> BN partial sums
// One block of 1024 threads per batch row. All intermediates stay in LDS.
// Weights (~1.6 MB total) are L2-resident after first touch per XCD.
// ---------------------------------------------------------------------------
__global__ __launch_bounds__(1024, 8) void fused_k(
    const float* __restrict__ hk, const float* __restrict__ hv,
    const float* __restrict__ y_1, const float* __restrict__ c_1,
    const float* __restrict__ sh_1, const float* __restrict__ sc_1,
    const float* __restrict__ mask,
    const float* __restrict__ W_ih0, const float* __restrict__ W_hh0,
    const float* __restrict__ b_ih0, const float* __restrict__ b_hh0,
    const float* __restrict__ W_ih1, const float* __restrict__ W_hh1,
    const float* __restrict__ b_ih1, const float* __restrict__ b_hh1,
    const float* __restrict__ W1, const float* __restrict__ b1,
    const float* __restrict__ W2, const float* __restrict__ b2,
    float* __restrict__ sh0_out, float* __restrict__ sc0_out,
    float* __restrict__ sh1_out, float* __restrict__ sc1_out,
    float* __restrict__ c_out, float* __restrict__ att_out,
    float* __restrict__ bn_sum, float* __restrict__ bn_sumsq)
{
    const int b = blockIdx.x;
    const int tid = threadIdx.x;
    const int w = tid >> 6;       // wave 0..15
    const int l = tid & 63;       // lane
    const int half = l >> 5;
    const int l32 = l & 31;

    __shared__ __align__(16) float xs[512];    // [y_1(256) | c_1(128) | h0_prev(128)]
    __shared__ __align__(16) float hs[256];    // [sh0(128) | h1_prev(128)]
    __shared__ __align__(16) float gs[512];    // gate pre-activations (reused)
    __shared__ __align__(16) float shv[Hd];    // sh1
    __shared__ __align__(16) float cvec[Hd];   // context
    __shared__ __align__(16) float sc[Tt];
    __shared__ __align__(16) float ctx[16][Hd];
    __shared__ float red[16];
    __shared__ float bcast[2];

    // ---- stage inputs for LSTM0 (and h_prev for LSTM1) ----
    if (tid < 512) {
        const int i = tid;
        float v;
        if (i < Ed)            v = y_1[(size_t)b * Ed + i];
        else if (i < Ed + Hd)  v = c_1[(size_t)b * Hd + (i - Ed)];
        else                   v = sh_1[(size_t)b * Hd + (i - Ed - Hd)];    // sh_1[0]
        xs[i] = v;
    } else if (tid < 640) {
        hs[Hd + (tid - 512)] = sh_1[(size_t)Bsz * Hd + (size_t)b * Hd + (tid - 512)]; // sh_1[1]
    }
    __syncthreads();

    // ---- LSTM0 gates: g = tid>>1, split-K halves reduced via shfl ----
    {
        const int g = tid >> 1;
        const int kh = tid & 1;
        float a0 = 0.f, a1 = 0.f;
        if (kh == 0) {
            const float* wp = W_ih0 + (size_t)g * 384;
            for (int k = 0; k < 256; k += 8) {
                float4 u = *(const float4*)(wp + k);
                float4 x = *(const float4*)(&xs[k]);
                a0 += u.x * x.x + u.y * x.y + u.z * x.z + u.w * x.w;
                float4 u2 = *(const float4*)(wp + k + 4);
                float4 x2 = *(const float4*)(&xs[k + 4]);
                a1 += u2.x * x2.x + u2.y * x2.y + u2.z * x2.z + u2.w * x2.w;
            }
        } else {
            const float* wp = W_ih0 + (size_t)g * 384 + 256;
            for (int k = 0; k < 128; k += 4) {
                float4 u = *(const float4*)(wp + k);
                float4 x = *(const float4*)(&xs[256 + k]);
                a0 += u.x * x.x + u.y * x.y + u.z * x.z + u.w * x.w;
            }
            const float* up = W_hh0 + (size_t)g * Hd;
            for (int k = 0; k < 128; k += 4) {
                float4 u = *(const float4*)(up + k);
                float4 x = *(const float4*)(&xs[384 + k]);
                a1 += u.x * x.x + u.y * x.y + u.z * x.z + u.w * x.w;
            }
        }
        float acc = a0 + a1;
        acc += __shfl_xor(acc, 1);
        if (kh == 0) gs[g] = acc + b_ih0[g] + b_hh0[g];
    }
    __syncthreads();

    // ---- LSTM0 cell update ----
    if (tid < Hd) {
        const int h = tid;
        const float ig = gs[h], fg = gs[Hd + h], gg = gs[2 * Hd + h], og = gs[3 * Hd + h];
        const float cp = sc_1[(size_t)b * Hd + h];                          // sc_1[0]
        const float cn = sigm(fg) * cp + sigm(ig) * tanhf(gg);
        const float hn = sigm(og) * tanhf(cn);
        sc0_out[(size_t)b * Hd + h] = cn;
        sh0_out[(size_t)b * Hd + h] = hn;
        hs[h] = hn;
    }
    __syncthreads();

    // ---- LSTM1 gates ----
    {
        const int g = tid >> 1;
        const int kh = tid & 1;
        const float* wp = (kh == 0) ? (W_ih1 + (size_t)g * Hd) : (W_hh1 + (size_t)g * Hd);
        const float* xp = (kh == 0) ? &hs[0] : &hs[Hd];
        float a0 = 0.f;
        for (int k = 0; k < 128; k += 4) {
            float4 u = *(const float4*)(wp + k);
            float4 x = *(const float4*)(xp + k);
            a0 += u.x * x.x + u.y * x.y + u.z * x.z + u.w * x.w;
        }
        a0 += __shfl_xor(a0, 1);
        if (kh == 0) gs[g] = a0 + b_ih1[g] + b_hh1[g];
    }
    __syncthreads();

    // ---- LSTM1 cell update ----
    if (tid < Hd) {
        const int h = tid;
        const float ig = gs[h], fg = gs[Hd + h], gg = gs[2 * Hd + h], og = gs[3 * Hd + h];
        const float cp = sc_1[(size_t)Bsz * Hd + (size_t)b * Hd + h];       // sc_1[1]
        const float cn = sigm(fg) * cp + sigm(ig) * tanhf(gg);
        const float hn = sigm(og) * tanhf(cn);
        sc1_out[(size_t)b * Hd + h] = cn;
        sh1_out[(size_t)b * Hd + h] = hn;
        shv[h] = hn;
    }
    __syncthreads();

    // ---- attention scores: sc[t] = hk[b,t,:] . sh1 ----
    const float* hkb = hk + (size_t)b * Tt * Hd;
    const float* hvb = hv + (size_t)b * Tt * Hd;
    const float4 s4 = *(const float4*)(&shv[l32 * 4]);

    for (int tp = w; tp < Tt / 2; tp += 32) {
        const int t0 = tp * 2;
        const int t1 = t0 + 32;
        const float4 v0 = *(const float4*)(hkb + (size_t)t0 * Hd + l * 4);
        const float4 v1 = *(const float4*)(hkb + (size_t)t1 * Hd + l * 4);
        float p0 = v0.x * s4.x + v0.y * s4.y + v0.z * s4.z + v0.w * s4.w;
        float p1 = v1.x * s4.x + v1.y * s4.y + v1.z * s4.z + v1.w * s4.w;
        p0 += __shfl_xor(p0, 1);  p1 += __shfl_xor(p1, 1);
        p0 += __shfl_xor(p0, 2);  p1 += __shfl_xor(p1, 2);
        p0 += __shfl_xor(p0, 4);  p1 += __shfl_xor(p1, 4);
        p0 += __shfl_xor(p0, 8);  p1 += __shfl_xor(p1, 8);
        p0 += __shfl_xor(p0, 16); p1 += __shfl_xor(p1, 16);
        if (l32 == 0) {
            sc[t0 + half] = p0;
            sc[t1 + half] = p1;
        }
    }
    __syncthreads();

    // ---- softmax max ----
    float m = fmaxf(sc[tid], sc[tid + 1024]);
    for (int off = 1; off <= 32; off <<= 1) m = fmaxf(m, __shfl_xor(m, off));
    if (l == 0) red[w] = m;
    __syncthreads();
    if (tid == 0) {
        float mm = red[0];
        for (int i = 1; i < 16; i++) mm = fmaxf(mm, red[i]);
        bcast[0] = mm;
    }
    __syncthreads();
    const float M = bcast[0];

    // ---- exp * mask, sum ----
    const float* maskb = mask + (size_t)b * Tt;
    const float e0 = __expf(sc[tid] - M) * maskb[tid];
    const float e1 = __expf(sc[tid + 1024] - M) * maskb[tid + 1024];
    sc[tid] = e0;
    sc[tid + 1024] = e1;
    float s = e0 + e1;
    for (int off = 1; off <= 32; off <<= 1) s += __shfl_xor(s, off);
    if (l == 0) red[w] = s;
    __syncthreads();
    if (tid == 0) {
        float ss = 0.f;
        for (int i = 0; i < 16; i++) ss += red[i];
        bcast[1] = 1.0f / ss;
    }
    __syncthreads();
    const float inv = bcast[1];

    if (b == 0) {
        att_out[tid] = sc[tid] * inv;
        att_out[tid + 1024] = sc[tid + 1024] * inv;
    }

    // ---- context: c[h] = sum_t attn[t] * hv[b,t,h] ----
    float4 acc = {0.f, 0.f, 0.f, 0.f};
    for (int tp = w; tp < Tt / 2; tp += 32) {
        const int t0 = tp * 2;
        const int t1 = t0 + 32;
        const float a0 = sc[t0 + half] * inv;
        const float a1 = sc[t1 + half] * inv;
        const float4 v0 = *(const float4*)(hvb + (size_t)t0 * Hd + l * 4);
        const float4 v1 = *(const float4*)(hvb + (size_t)t1 * Hd + l * 4);
        acc.x += a0 * v0.x + a1 * v1.x;
        acc.y += a0 * v0.y + a1 * v1.y;
        acc.z += a0 * v0.z + a1 * v1.z;
        acc.w += a0 * v0.w + a1 * v1.w;
    }
    acc.x += __shfl_xor(acc.x, 32);
    acc.y += __shfl_xor(acc.y, 32);
    acc.z += __shfl_xor(acc.z, 32);
    acc.w += __shfl_xor(acc.w, 32);
    if (half == 0) *(float4*)(&ctx[w][l32 * 4]) = acc;
    __syncthreads();
    if (tid < Hd) {
        float v = 0.f;
        for (int i = 0; i < 16; i++) v += ctx[i][tid];
        cvec[tid] = v;
        c_out[(size_t)b * Hd + tid] = v;
    }
    __syncthreads();

    // ---- BN partial sums: pre[h] = sh1.W1[h] + c.W2[h] + b1[h] + b2[h] ----
    if (tid < 512) {
        const int h = tid >> 2, q = tid & 3;
        const float* w1 = W1 + (size_t)h * Hd + q * 32;
        const float* w2 = W2 + (size_t)h * Hd + q * 32;
        const float* x1 = &shv[q * 32];
        const float* x2 = &cvec[q * 32];
        float a0 = 0.f;
        for (int k = 0; k < 32; k += 4) {
            float4 u = *(const float4*)(w1 + k);
            float4 x = *(const float4*)(x1 + k);
            a0 += u.x * x.x + u.y * x.y + u.z * x.z + u.w * x.w;
            float4 u2 = *(const float4*)(w2 + k);
            float4 y = *(const float4*)(x2 + k);
            a0 += u2.x * y.x + u2.y * y.y + u2.z * y.z + u2.w * y.w;
        }
        a0 += __shfl_xor(a0, 1);
        a0 += __shfl_xor(a0, 2);
        if (q == 0) {
            const float pre = a0 + b1[h] + b2[h];
            atomicAdd(&bn_sum[h], pre);
            atomicAdd(&bn_sumsq[h], pre * pre);
        }
    }
}

// ---------------------------------------------------------------------------
// Head part 2: recompute pre, BN(train)+ReLU, out = act@W3.T + b3
// ---------------------------------------------------------------------------
__global__ __launch_bounds__(128) void head_out_k(
    const float* __restrict__ sh1, const float* __restrict__ cvec,
    const float* __restrict__ W1, const float* __restrict__ b1,
    const float* __restrict__ W2, const float* __restrict__ b2,
    const float* __restrict__ sum, const float* __restrict__ sumsq,
    const float* __restrict__ gamma, const float* __restrict__ beta,
    const float* __restrict__ W3, const float* __restrict__ b3,
    float* __restrict__ out)
{
    const int b = blockIdx.x;
    const int h = threadIdx.x;
    __shared__ __align__(16) float s1[Hd], s2[Hd], act[Hd];
    s1[h] = sh1[(size_t)b * Hd + h];
    s2[h] = cvec[(size_t)b * Hd + h];
    __syncthreads();
    const float* w1 = W1 + (size_t)h * Hd;
    const float* w2 = W2 + (size_t)h * Hd;
    float pre = b1[h] + b2[h];
    for (int k = 0; k < Hd; k += 4) {
        float4 a = *(const float4*)(w1 + k);
        float4 x = *(const float4*)(&s1[k]);
        pre += a.x * x.x + a.y * x.y + a.z * x.z + a.w * x.w;
        float4 bm = *(const float4*)(w2 + k);
        float4 y = *(const float4*)(&s2[k]);
        pre += bm.x * y.x + bm.y * y.y + bm.z * y.z + bm.w * y.w;
    }
    const float mean = sum[h] * (1.0f / (float)Bsz);
    const float var = sumsq[h] * (1.0f / (float)Bsz) - mean * mean;
    const float a = (pre - mean) * rsqrtf(var + 1e-5f) * gamma[h] + beta[h];
    act[h] = fmaxf(a, 0.0f);
    __syncthreads();
    if (h < Vv) {
        const float* w3 = W3 + (size_t)h * Hd;
        float o = b3[h];
        for (int k = 0; k < Hd; k += 4) {
            float4 a4 = *(const float4*)(w3 + k);
            float4 x = *(const float4*)(&act[k]);
            o += a4.x * x.x + a4.y * x.y + a4.z * x.z + a4.w * x.w;
        }
        out[(size_t)b * Vv + h] = o;
    }
}

extern "C" void kernel_launch(void* const* d_in, const int* in_sizes, int n_in,
                              void* d_out, int out_size, void* d_ws, size_t ws_size,
                              hipStream_t stream)
{
    const float* hk    = (const float*)d_in[0];
    const float* hv    = (const float*)d_in[1];
    const float* y_1   = (const float*)d_in[2];
    const float* c_1   = (const float*)d_in[3];
    const float* sh_1  = (const float*)d_in[4];   // [2,B,H]
    const float* sc_1  = (const float*)d_in[5];   // [2,B,H]
    const float* mask  = (const float*)d_in[6];
    const float* W_ih0 = (const float*)d_in[7];
    const float* W_hh0 = (const float*)d_in[8];
    const float* b_ih0 = (const float*)d_in[9];
    const float* b_hh0 = (const float*)d_in[10];
    const float* W_ih1 = (const float*)d_in[11];
    const float* W_hh1 = (const float*)d_in[12];
    const float* b_ih1 = (const float*)d_in[13];
    const float* b_hh1 = (const float*)d_in[14];
    const float* W1    = (const float*)d_in[15];
    const float* b1    = (const float*)d_in[16];
    const float* W2    = (const float*)d_in[17];
    const float* b2    = (const float*)d_in[18];
    const float* W3    = (const float*)d_in[19];
    const float* b3    = (const float*)d_in[20];
    const float* gamma = (const float*)d_in[21];
    const float* beta  = (const float*)d_in[22];

    float* out = (float*)d_out;
    float* o_out = out + OUT_OUT;
    float* o_c   = out + OUT_C;
    float* o_sh0 = out + OUT_SH0;
    float* o_sh1 = out + OUT_SH1;
    float* o_sc0 = out + OUT_SC0;
    float* o_sc1 = out + OUT_SC1;
    float* o_att = out + OUT_ATT;

    float* ws_sum   = (float*)d_ws;        // 128 floats
    float* ws_sumsq = ws_sum + Hd;         // 128 floats
    hipMemsetAsync(d_ws, 0, 2 * Hd * sizeof(float), stream);

    fused_k<<<Bsz, 1024, 0, stream>>>(
        hk, hv, y_1, c_1, sh_1, sc_1, mask,
        W_ih0, W_hh0, b_ih0, b_hh0,
        W_ih1, W_hh1, b_ih1, b_hh1,
        W1, b1, W2, b2,
        o_sh0, o_sc0, o_sh1, o_sc1, o_c, o_att,
        ws_sum, ws_sumsq);

    head_out_k<<<Bsz, 128, 0, stream>>>(o_sh1, o_c, W1, b1, W2, b2, ws_sum, ws_sumsq,
                                        gamma, beta, W3, b3, o_out);
}